// Round 1
// baseline (57756.403 us; speedup 1.0000x reference)
//
#include <hip/hip_runtime.h>
#include <math.h>

#define IQ     64
#define C_CH   256
#define T_SEQ  1024
#define NSTEP  (IQ * T_SEQ)

// ---------------------------------------------------------------------------
// GEMM in [iq][c][t] layout:
//   Out[iq][c][t] = act( sum_j A[c][j] * In[iq][j][t] (+ bias[c]) )
// Tiles: 64 c x 64 t per block, K staged in chunks of 64. 256 threads.
// Used for (A=M, In=u)  -> Uproj   (no activation)
// and      (A=H, In=X)  -> Y       (sigmoid + bias)
// ---------------------------------------------------------------------------
template <bool SIG>
__global__ void __launch_bounds__(256) gemm_ct(const float* __restrict__ A,
                                               const float* __restrict__ In,
                                               const float* __restrict__ bias,
                                               float* __restrict__ Out) {
    __shared__ float aT[64][65];  // [jj][c]  (A transposed tile, padded)
    __shared__ float bI[64][68];  // [jj][t]  (In tile, padded, 16B-aligned rows)

    const int tid = threadIdx.x;
    const int t0  = blockIdx.x * 64;
    const int c0  = blockIdx.y * 64;
    const int iq  = blockIdx.z;

    const int tt = tid & 15;   // t-quad index (compute mapping)
    const int cc = tid >> 4;   // c-quad index
    const int lr = tid >> 2;   // row for loads
    const int lq = tid & 3;    // quad-column for loads

    float acc[4][4];
#pragma unroll
    for (int m = 0; m < 4; ++m)
#pragma unroll
        for (int n = 0; n < 4; ++n) acc[m][n] = 0.f;

    for (int kc = 0; kc < 4; ++kc) {
        // Stage A rows c0..c0+63, j = kc*64 .. kc*64+63 (transposed into aT)
        const float* Ar = A + (size_t)(c0 + lr) * 256 + kc * 64;
#pragma unroll
        for (int k2 = 0; k2 < 4; ++k2) {
            float4 v = *(const float4*)(Ar + lq * 4 + k2 * 16);
            int jj = lq * 4 + k2 * 16;
            aT[jj + 0][lr] = v.x;
            aT[jj + 1][lr] = v.y;
            aT[jj + 2][lr] = v.z;
            aT[jj + 3][lr] = v.w;
        }
        // Stage In rows j = kc*64 .. +63, t = t0 .. t0+63
        const float* Ir = In + ((size_t)iq * 256 + kc * 64 + lr) * 1024 + t0;
#pragma unroll
        for (int k2 = 0; k2 < 4; ++k2) {
            float4 v = *(const float4*)(Ir + lq * 4 + k2 * 16);
            *(float4*)&bI[lr][lq * 4 + k2 * 16] = v;
        }
        __syncthreads();

#pragma unroll 8
        for (int jj = 0; jj < 64; ++jj) {
            const float a0 = aT[jj][cc * 4 + 0];
            const float a1 = aT[jj][cc * 4 + 1];
            const float a2 = aT[jj][cc * 4 + 2];
            const float a3 = aT[jj][cc * 4 + 3];
            const float4 b4 = *(const float4*)&bI[jj][tt * 4];
            acc[0][0] = fmaf(a0, b4.x, acc[0][0]);
            acc[0][1] = fmaf(a0, b4.y, acc[0][1]);
            acc[0][2] = fmaf(a0, b4.z, acc[0][2]);
            acc[0][3] = fmaf(a0, b4.w, acc[0][3]);
            acc[1][0] = fmaf(a1, b4.x, acc[1][0]);
            acc[1][1] = fmaf(a1, b4.y, acc[1][1]);
            acc[1][2] = fmaf(a1, b4.z, acc[1][2]);
            acc[1][3] = fmaf(a1, b4.w, acc[1][3]);
            acc[2][0] = fmaf(a2, b4.x, acc[2][0]);
            acc[2][1] = fmaf(a2, b4.y, acc[2][1]);
            acc[2][2] = fmaf(a2, b4.z, acc[2][2]);
            acc[2][3] = fmaf(a2, b4.w, acc[2][3]);
            acc[3][0] = fmaf(a3, b4.x, acc[3][0]);
            acc[3][1] = fmaf(a3, b4.y, acc[3][1]);
            acc[3][2] = fmaf(a3, b4.z, acc[3][2]);
            acc[3][3] = fmaf(a3, b4.w, acc[3][3]);
        }
        __syncthreads();
    }

#pragma unroll
    for (int m = 0; m < 4; ++m) {
        const int c = c0 + cc * 4 + m;
        float4 v;
        if constexpr (SIG) {
            const float bb = bias[c];
            v.x = __fdividef(1.f, 1.f + __expf(-(acc[m][0] + bb)));
            v.y = __fdividef(1.f, 1.f + __expf(-(acc[m][1] + bb)));
            v.z = __fdividef(1.f, 1.f + __expf(-(acc[m][2] + bb)));
            v.w = __fdividef(1.f, 1.f + __expf(-(acc[m][3] + bb)));
        } else {
            v.x = acc[m][0];
            v.y = acc[m][1];
            v.z = acc[m][2];
            v.w = acc[m][3];
        }
        *(float4*)(Out + ((size_t)iq * 256 + c) * 1024 + t0 + tt * 4) = v;
    }
}

// ---------------------------------------------------------------------------
// Sequential scan: single workgroup, 1024 threads (16 waves on 1 CU).
//   x_{s+1} = x_s + dt*(-x_s + W @ tanh(x_s) + Uproj[s])
// Thread (q = tid>>8, i = tid&255) holds W[i][64q..64q+63] in VGPRs and
// accumulates a partial dot with tanh(x) broadcast from LDS.
// Uproj is read (and x written out) in 16-step coalesced batches via LDS.
// Up is in [iq][c][t] layout (out0 region); Xout written [iq][c][t] (out1).
// ---------------------------------------------------------------------------
__global__ void __launch_bounds__(1024) scan_kernel(const float* __restrict__ W,
                                                    const float* __restrict__ Up,
                                                    const float* __restrict__ dtp,
                                                    float* __restrict__ Xout) {
    __shared__ float tx[256];        // tanh(x)
    __shared__ float part[4][256];   // partial sums
    __shared__ float upb[16][256];   // staged Uproj, [t&15][c]
    __shared__ float xh[16][256];    // x history for batched writeback

    const int tid = threadIdx.x;
    const int q = tid >> 8;
    const int i = tid & 255;
    const float dt = *dtp;

    // Preload W[i][64q .. 64q+63] into registers (one-time gather, 256 KB).
    float w[64];
    {
        const float* Wr = W + (size_t)i * 256 + q * 64;
#pragma unroll
        for (int k = 0; k < 16; ++k) {
            float4 v = *(const float4*)(Wr + 4 * k);
            w[4 * k + 0] = v.x;
            w[4 * k + 1] = v.y;
            w[4 * k + 2] = v.z;
            w[4 * k + 3] = v.w;
        }
    }

    float x = 0.f;  // valid for leader threads (tid < 256)
    if (tid < 256) tx[i] = 0.f;  // tanh(0)
    __syncthreads();

    const int cld = tid >> 2;  // refill/flush mapping: channel
    const int tq  = tid & 3;   // t-quad within 16-step batch

    for (int s = 0; s < NSTEP; ++s) {
        if ((s & 15) == 0) {
            // Coalesced refill of 16 steps of Uproj into LDS.
            const int iq = s >> 10;
            const int t0 = s & 1023;
            float4 v = *(const float4*)(Up + ((size_t)iq * 256 + cld) * 1024 + t0 + tq * 4);
            upb[tq * 4 + 0][cld] = v.x;
            upb[tq * 4 + 1][cld] = v.y;
            upb[tq * 4 + 2][cld] = v.z;
            upb[tq * 4 + 3][cld] = v.w;
        }

        // Matvec partial: sum_j W[i][64q+j] * tanh(x)[64q+j]
        float p0 = 0.f, p1 = 0.f, p2 = 0.f, p3 = 0.f;
#pragma unroll
        for (int k = 0; k < 16; ++k) {
            const float4 t4 = *(const float4*)&tx[(q << 6) + (k << 2)];
            p0 = fmaf(w[4 * k + 0], t4.x, p0);
            p1 = fmaf(w[4 * k + 1], t4.y, p1);
            p2 = fmaf(w[4 * k + 2], t4.z, p2);
            p3 = fmaf(w[4 * k + 3], t4.w, p3);
        }
        part[q][i] = (p0 + p1) + (p2 + p3);
        __syncthreads();  // B1: partials + upb visible

        if (tid < 256) {
            const float sum = part[0][i] + part[1][i] + part[2][i] + part[3][i];
            const float inp = sum + upb[s & 15][i];
            x = fmaf(dt, inp - x, x);  // x + dt*(-x + inp)
            xh[s & 15][i] = x;
            // stable fast tanh: sign(x) * (1-e)/(1+e), e = exp(-2|x|)
            const float a  = fabsf(x);
            const float e  = __expf(-2.f * a);
            const float th = (1.f - e) * __fdividef(1.f, 1.f + e);
            tx[i] = copysignf(th, x);
        }
        __syncthreads();  // B2: tx / xh ready

        if ((s & 15) == 15) {
            // Coalesced flush of 16 steps of x to out1 ([iq][c][t]).
            const int iq = s >> 10;
            const int t0 = (s & 1023) - 15;
            float4 v;
            v.x = xh[tq * 4 + 0][cld];
            v.y = xh[tq * 4 + 1][cld];
            v.z = xh[tq * 4 + 2][cld];
            v.w = xh[tq * 4 + 3][cld];
            *(float4*)(Xout + ((size_t)iq * 256 + cld) * 1024 + t0 + tq * 4) = v;
        }
    }
}

// ---------------------------------------------------------------------------
extern "C" void kernel_launch(void* const* d_in, const int* in_sizes, int n_in,
                              void* d_out, int out_size, void* d_ws, size_t ws_size,
                              hipStream_t stream) {
    const float* u  = (const float*)d_in[0];
    const float* dt = (const float*)d_in[1];
    const float* W  = (const float*)d_in[2];
    const float* M  = (const float*)d_in[3];
    const float* H  = (const float*)d_in[4];
    const float* b  = (const float*)d_in[5];

    float* out0 = (float*)d_out;                        // outputs region (Y)
    float* out1 = out0 + (size_t)IQ * C_CH * T_SEQ;     // membrane region (X)

    dim3 ggrid(T_SEQ / 64, C_CH / 64, IQ);

    // 1) Uproj[iq][c][t] = M @ u_iq  -> staged in out0 (overwritten by Y later)
    gemm_ct<false><<<ggrid, 256, 0, stream>>>(M, u, nullptr, out0);

    // 2) Sequential scan over 65536 steps; writes membrane potentials to out1
    scan_kernel<<<1, 1024, 0, stream>>>(W, out0, dt, out1);

    // 3) Y[iq][c][t] = sigmoid(H @ X_iq + b) -> out0
    gemm_ct<true><<<ggrid, 256, 0, stream>>>(H, out1, b, out0);
}